// Round 10
// baseline (513.594 us; speedup 1.0000x reference)
//
#include <hip/hip_runtime.h>
#include <stdint.h>

#define NN 10000
#define NE 160000

typedef short short8 __attribute__((ext_vector_type(8)));
typedef float f32x4 __attribute__((ext_vector_type(4)));

// ---------- bf16 helpers (internal staging format; I/O is f32) ----------
__device__ __forceinline__ float bf2f(unsigned short u) {
    return __uint_as_float(((uint32_t)u) << 16);
}
__device__ __forceinline__ float bflo(uint32_t u) { return __uint_as_float(u << 16); }
__device__ __forceinline__ float bfhi(uint32_t u) { return __uint_as_float(u & 0xffff0000u); }
__device__ __forceinline__ unsigned short f2bf(float f) {
    uint32_t u = __float_as_uint(f);
    u += 0x7fffu + ((u >> 16) & 1u);   // RNE
    return (unsigned short)(u >> 16);
}
__device__ __forceinline__ uint32_t pack2(float lo, float hi) {
    return (uint32_t)f2bf(lo) | ((uint32_t)f2bf(hi) << 16);
}
__device__ __forceinline__ float silu2(float x) {
    return 1.679177f * x / (1.f + __expf(-x));
}

// ---------------------------------------------------------------------------
// k_wup: transpose up-weights -> [v][u] bf16 with 1/sqrt(128) folded in.
// ---------------------------------------------------------------------------
__global__ __launch_bounds__(256) void k_wup(const float* __restrict__ Wu0,
                                             const float* __restrict__ Wu1,
                                             unsigned short* __restrict__ w0T,
                                             unsigned short* __restrict__ w1T) {
    const float s = 0.08838834764831845f;
    for (int i = threadIdx.x + blockIdx.x * 256; i < 16384; i += 256 * 64) {
        int u = i >> 7, v = i & 127;
        w0T[v * 128 + u] = f2bf(Wu0[i] * s);
        w1T[v * 128 + u] = f2bf(Wu1[i] * s);
    }
}

// ---------------------------------------------------------------------------
// k_prep: nf (f32, [n][512]) -> bf16 MFMA A-planes.
// ---------------------------------------------------------------------------
__global__ __launch_bounds__(256) void k_prep(const float* __restrict__ nf,
                                              unsigned short* __restrict__ x0b,
                                              unsigned short* __restrict__ x1b) {
    int idx = blockIdx.x * 256 + threadIdx.x;     // 1,280,000
    int n = idx >> 7, u = idx & 127;
    const float* row = nf + (size_t)n * 512;
    x0b[(size_t)n * 128 + u] = f2bf(row[u]);
    const float* p = row + 128 + u * 3;
    x1b[(size_t)n * 128 + u]                = f2bf(p[0]);
    x1b[1280000 + (size_t)n * 128 + u]      = f2bf(p[1]);
    x1b[2560000 + (size_t)n * 128 + u]      = f2bf(p[2]);
}

// ---------------------------------------------------------------------------
// k_upg (MFMA): y0 = x0 @ W0, y1[m] = x1[m] @ W1. (R9 proven)
// xw[n]: [y0 (128) | y1 m-major: 128 + m*128 + v]
// ---------------------------------------------------------------------------
__global__ __launch_bounds__(256) void k_upg(const unsigned short* __restrict__ x0b,
                                             const unsigned short* __restrict__ x1b,
                                             const unsigned short* __restrict__ w0T,
                                             const unsigned short* __restrict__ w1T,
                                             float* __restrict__ xw) {
    int wave = threadIdx.x >> 6, lane = threadIdx.x & 63;
    int wid = blockIdx.x * 4 + wave;              // 1250
    if (wid >= 1250) return;
    int tile = wid >> 1, half = wid & 1;
    int n0 = tile * 16;
    int lm = lane & 15, lq = lane >> 4;

    uint4 A0[4], A1[3][4];
    const unsigned short* a0r = x0b + (size_t)(n0 + lm) * 128 + lq * 8;
#pragma unroll
    for (int kf = 0; kf < 4; ++kf) A0[kf] = *(const uint4*)(a0r + kf * 32);
#pragma unroll
    for (int m = 0; m < 3; ++m) {
        const unsigned short* a1r = x1b + 1280000 * (size_t)m + (size_t)(n0 + lm) * 128 + lq * 8;
#pragma unroll
        for (int kf = 0; kf < 4; ++kf) A1[m][kf] = *(const uint4*)(a1r + kf * 32);
    }

    for (int vq = 0; vq < 4; ++vq) {
        int vt = half * 4 + vq;
        const unsigned short* b0r = w0T + (vt * 16 + lm) * 128 + lq * 8;
        const unsigned short* b1r = w1T + (vt * 16 + lm) * 128 + lq * 8;
        f32x4 acc0 = {0.f, 0.f, 0.f, 0.f};
#pragma unroll
        for (int kf = 0; kf < 4; ++kf) {
            short8 b = __builtin_bit_cast(short8, *(const uint4*)(b0r + kf * 32));
            acc0 = __builtin_amdgcn_mfma_f32_16x16x32_bf16(
                __builtin_bit_cast(short8, A0[kf]), b, acc0, 0, 0, 0);
        }
        f32x4 acc1[3];
#pragma unroll
        for (int m = 0; m < 3; ++m) acc1[m] = (f32x4){0.f, 0.f, 0.f, 0.f};
#pragma unroll
        for (int kf = 0; kf < 4; ++kf) {
            short8 b = __builtin_bit_cast(short8, *(const uint4*)(b1r + kf * 32));
#pragma unroll
            for (int m = 0; m < 3; ++m)
                acc1[m] = __builtin_amdgcn_mfma_f32_16x16x32_bf16(
                    __builtin_bit_cast(short8, A1[m][kf]), b, acc1[m], 0, 0, 0);
        }
        int col = vt * 16 + lm;
#pragma unroll
        for (int r = 0; r < 4; ++r) {
            float* o = xw + (size_t)(n0 + lq * 4 + r) * 512;
            o[col] = acc0[r];
            o[128 + col] = acc1[0][r];
            o[256 + col] = acc1[1][r];
            o[384 + col] = acc1[2][r];
        }
    }
}

// ---------------------------------------------------------------------------
// k_wmlp: pre-transpose+scale MLP weights to bf16.
// ---------------------------------------------------------------------------
__global__ __launch_bounds__(256) void k_wmlp(const float* __restrict__ W1,
                                              const float* __restrict__ W2,
                                              const float* __restrict__ W3,
                                              unsigned short* __restrict__ w1Tp,
                                              unsigned short* __restrict__ w2T,
                                              unsigned short* __restrict__ w3T) {
    int t = threadIdx.x;
    for (int i = t; i < 2048; i += 256) {
        int jj = i >> 5, k = i & 31;
        w1Tp[i] = (k < 8) ? f2bf(W1[k * 64 + jj] * 0.3535533905932738f) : 0;
    }
    for (int i = t; i < 4096; i += 256) {
        int jj = i >> 6, k = i & 63;
        w2T[i] = f2bf(W2[k * 64 + jj] * 0.125f);
        w3T[i] = f2bf(W3[k * 64 + jj] * 0.125f);
    }
}

// ---------------------------------------------------------------------------
// K2 (MFMA): edge MLP stages 1-3 -> h3 (NE x 64 bf16). (R7 proven)
// ---------------------------------------------------------------------------
__global__ __launch_bounds__(256) void k_mlp(const float* __restrict__ ef,
                                             const unsigned short* __restrict__ w1Tp,
                                             const unsigned short* __restrict__ w2T,
                                             const unsigned short* __restrict__ w3T,
                                             unsigned short* __restrict__ h3w) {
    __shared__ __align__(16) unsigned short hs_all[4][64 * 72];
    int wave = threadIdx.x >> 6, lane = threadIdx.x & 63;
    int lm = lane & 15, lq = lane >> 4;
    int e0 = blockIdx.x * 256 + wave * 64;
    unsigned short* h = hs_all[wave];

    // stage 1: K=32 (8 real, zero-padded)
    uint4 A1[4];
#pragma unroll
    for (int mt = 0; mt < 4; ++mt)
        A1[mt] = *(const uint4*)(w1Tp + (mt * 16 + lm) * 32 + lq * 8);
#pragma unroll
    for (int nt = 0; nt < 4; ++nt) {
        uint4 b = {0, 0, 0, 0};
        if (lq == 0) {
            const float4* p = (const float4*)(ef + (size_t)(e0 + nt * 16 + lm) * 8);
            float4 x = p[0], y = p[1];
            b.x = pack2(x.x, x.y); b.y = pack2(x.z, x.w);
            b.z = pack2(y.x, y.y); b.w = pack2(y.z, y.w);
        }
        short8 bb = __builtin_bit_cast(short8, b);
        unsigned short* hrow = h + (nt * 16 + lm) * 72;
#pragma unroll
        for (int mt = 0; mt < 4; ++mt) {
            f32x4 acc = {0.f, 0.f, 0.f, 0.f};
            acc = __builtin_amdgcn_mfma_f32_16x16x32_bf16(
                __builtin_bit_cast(short8, A1[mt]), bb, acc, 0, 0, 0);
            uint2 v;
            v.x = pack2(silu2(acc[0]), silu2(acc[1]));
            v.y = pack2(silu2(acc[2]), silu2(acc[3]));
            *(uint2*)(hrow + mt * 16 + lq * 4) = v;
        }
    }

    // stage 2: K=64
    uint4 A2[4][2];
#pragma unroll
    for (int mt = 0; mt < 4; ++mt)
#pragma unroll
        for (int kf = 0; kf < 2; ++kf)
            A2[mt][kf] = *(const uint4*)(w2T + (mt * 16 + lm) * 64 + kf * 32 + lq * 8);
#pragma unroll
    for (int nt = 0; nt < 4; ++nt) {
        unsigned short* hrow = h + (nt * 16 + lm) * 72;
        short8 B0 = __builtin_bit_cast(short8, *(const uint4*)(hrow + lq * 8));
        short8 B1 = __builtin_bit_cast(short8, *(const uint4*)(hrow + 32 + lq * 8));
#pragma unroll
        for (int mt = 0; mt < 4; ++mt) {
            f32x4 acc = {0.f, 0.f, 0.f, 0.f};
            acc = __builtin_amdgcn_mfma_f32_16x16x32_bf16(
                __builtin_bit_cast(short8, A2[mt][0]), B0, acc, 0, 0, 0);
            acc = __builtin_amdgcn_mfma_f32_16x16x32_bf16(
                __builtin_bit_cast(short8, A2[mt][1]), B1, acc, 0, 0, 0);
            uint2 v;
            v.x = pack2(silu2(acc[0]), silu2(acc[1]));
            v.y = pack2(silu2(acc[2]), silu2(acc[3]));
            *(uint2*)(hrow + mt * 16 + lq * 4) = v;
        }
    }

    // stage 3: K=64
    uint4 A3[4][2];
#pragma unroll
    for (int mt = 0; mt < 4; ++mt)
#pragma unroll
        for (int kf = 0; kf < 2; ++kf)
            A3[mt][kf] = *(const uint4*)(w3T + (mt * 16 + lm) * 64 + kf * 32 + lq * 8);
#pragma unroll
    for (int nt = 0; nt < 4; ++nt) {
        unsigned short* hrow = h + (nt * 16 + lm) * 72;
        short8 B0 = __builtin_bit_cast(short8, *(const uint4*)(hrow + lq * 8));
        short8 B1 = __builtin_bit_cast(short8, *(const uint4*)(hrow + 32 + lq * 8));
#pragma unroll
        for (int mt = 0; mt < 4; ++mt) {
            f32x4 acc = {0.f, 0.f, 0.f, 0.f};
            acc = __builtin_amdgcn_mfma_f32_16x16x32_bf16(
                __builtin_bit_cast(short8, A3[mt][0]), B0, acc, 0, 0, 0);
            acc = __builtin_amdgcn_mfma_f32_16x16x32_bf16(
                __builtin_bit_cast(short8, A3[mt][1]), B1, acc, 0, 0, 0);
            uint2 v;
            v.x = pack2(silu2(acc[0]), silu2(acc[1]));
            v.y = pack2(silu2(acc[2]), silu2(acc[3]));
            *(uint2*)(hrow + mt * 16 + lq * 4) = v;
        }
    }

    // flush: coalesced 16B/lane stores
    const unsigned short* hr = h + lane * 72;
    uint4* og = (uint4*)(h3w + (size_t)(e0 + lane) * 64);
#pragma unroll
    for (int q = 0; q < 8; ++q) og[q] = *(const uint4*)(hr + q * 8);
}

// ---------------------------------------------------------------------------
// K3: CSR build by receiver (zero -> histogram -> scan -> fill)
// ---------------------------------------------------------------------------
__global__ void k_zero(int* __restrict__ p, int n) {
    int i = blockIdx.x * 256 + threadIdx.x;
    if (i < n) p[i] = 0;
}
__global__ void k_hist(const int* __restrict__ ei, int* __restrict__ counts) {
    int e = blockIdx.x * 256 + threadIdx.x;
    if (e < NE) atomicAdd(&counts[ei[NE + e]], 1);
}
__global__ __launch_bounds__(1024) void k_scan(const int* __restrict__ counts,
                                               int* __restrict__ offs,
                                               int* __restrict__ cursor) {
    __shared__ int sums[1024];
    int t = threadIdx.x;
    int base = t * 10;
    int s = 0;
    for (int i = 0; i < 10; ++i) {
        int idx = base + i;
        if (idx < NN) s += counts[idx];
    }
    sums[t] = s;
    __syncthreads();
    for (int d = 1; d < 1024; d <<= 1) {
        int v = (t >= d) ? sums[t - d] : 0;
        __syncthreads();
        if (t >= d) sums[t] += v;
        __syncthreads();
    }
    int run = (t == 0) ? 0 : sums[t - 1];
    for (int i = 0; i < 10; ++i) {
        int idx = base + i;
        if (idx < NN) {
            offs[idx] = run;
            cursor[idx] = run;
            run += counts[idx];
        }
    }
    if (t == 0) offs[NN] = NE;
}
__global__ void k_fill(const int* __restrict__ ei, int* __restrict__ cursor,
                       int* __restrict__ elist, int* __restrict__ rix) {
    int e = blockIdx.x * 256 + threadIdx.x;
    if (e < NE) {
        int r = ei[NE + e];
        int slot = atomicAdd(&cursor[r], 1);
        elist[slot] = e;
        rix[slot] = r;
    }
}
// k_gather: resolve per-slot sender + edge_attrs
__global__ void k_gather(const int* __restrict__ ei, const float* __restrict__ ea,
                         const int* __restrict__ elist,
                         int* __restrict__ eis, float4* __restrict__ eap) {
    int i = blockIdx.x * 256 + threadIdx.x;
    if (i < NE) {
        int e = elist[i];
        eis[i] = ei[e];
        eap[i] = *(const float4*)(ea + (size_t)e * 4);
    }
}

// ---------------------------------------------------------------------------
// Weight transposes (bf16). k_w4t folds the 1/sqrt(64)=0.125 scale (exact).
// ---------------------------------------------------------------------------
__global__ void k_w4t(const float* __restrict__ W4, unsigned short* __restrict__ w4T) {
    int idx = blockIdx.x * 256 + threadIdx.x;   // 32768
    int k = idx >> 9, c = idx & 511;
    w4T[c * 64 + k] = f2bf(W4[idx] * 0.125f);
}
__global__ void k_wt2(const float* __restrict__ Wo0, const float* __restrict__ Wo1,
                      unsigned short* __restrict__ woT0, unsigned short* __restrict__ woT1) {
    int idx = blockIdx.x * 256 + threadIdx.x;   // 32768
    int u = idx >> 7, v = idx & 127;
    woT0[v * 256 + u] = f2bf(Wo0[idx]);
    woT1[v * 256 + u] = f2bf(Wo1[idx]);
}

// ---------------------------------------------------------------------------
// k_tpmsg (FUSED): per 64-slot chunk, phase A computes the 64x512 tpw tile
// with MFMA into LDS (bf16, rows padded to 520 shorts); phase B runs the
// k_msg2 tensor-product+reduce mapping straight from LDS. tpw never touches
// HBM. Accumulators persist across chunks; flush on receiver change; block-
// straddling receivers use f32 atomicAdd into zeroed msg.
// ---------------------------------------------------------------------------
__global__ __launch_bounds__(256) void k_tpmsg(const unsigned short* __restrict__ h3w,
                                               const unsigned short* __restrict__ w4T,
                                               const int* __restrict__ elist,
                                               const int* __restrict__ eis,
                                               const int* __restrict__ rix,
                                               const float4* __restrict__ eap,
                                               const int* __restrict__ offs,
                                               const float* __restrict__ xw,
                                               float* __restrict__ msg) {
    __shared__ __align__(16) unsigned short tile[64 * 520];
    int t = threadIdx.x;
    int wave = t >> 6, lane = t & 63;
    int lm = lane & 15, lq = lane >> 4;
    int blockStart = blockIdx.x * 256;
    int blockEnd = blockStart + 256;
    int j = t >> 6;
    int c0 = (t & 63) * 2;

    const unsigned short* aw = w4T + lm * 64 + lq * 8;

    float a0 = 0.f, a1 = 0.f, a2 = 0.f, a3 = 0.f, a4 = 0.f, a5 = 0.f;
    int curR = rix[blockStart];

    auto doFlush = [&](int r) {
        float* mr = msg + (size_t)r * 1024;
        bool bnd = (offs[r] < blockStart) || (offs[r + 1] > blockEnd);
        if (j == 0) {
            if (bnd) { atomicAdd(&mr[c0], a0); atomicAdd(&mr[c0 + 1], a1); }
            else { mr[c0] = a0; mr[c0 + 1] = a1; }
        } else if (j == 1) {
            if (bnd) {
                atomicAdd(&mr[256 + c0], a0); atomicAdd(&mr[256 + c0 + 1], a3);
                atomicAdd(&mr[512 + c0], a1); atomicAdd(&mr[512 + c0 + 1], a4);
                atomicAdd(&mr[768 + c0], a2); atomicAdd(&mr[768 + c0 + 1], a5);
            } else {
                mr[256 + c0] = a0; mr[256 + c0 + 1] = a3;
                mr[512 + c0] = a1; mr[512 + c0 + 1] = a4;
                mr[768 + c0] = a2; mr[768 + c0 + 1] = a5;
            }
        } else if (j == 2) {
            if (bnd) {
                atomicAdd(&mr[384 + c0], a0); atomicAdd(&mr[384 + c0 + 1], a3);
                atomicAdd(&mr[640 + c0], a1); atomicAdd(&mr[640 + c0 + 1], a4);
                atomicAdd(&mr[896 + c0], a2); atomicAdd(&mr[896 + c0 + 1], a5);
            } else {
                mr[384 + c0] = a0; mr[384 + c0 + 1] = a3;
                mr[640 + c0] = a1; mr[640 + c0 + 1] = a4;
                mr[896 + c0] = a2; mr[896 + c0 + 1] = a5;
            }
        } else {
            if (bnd) { atomicAdd(&mr[128 + c0], a0); atomicAdd(&mr[128 + c0 + 1], a1); }
            else { mr[128 + c0] = a0; mr[128 + c0 + 1] = a1; }
        }
        a0 = a1 = a2 = a3 = a4 = a5 = 0.f;
    };

    for (int chunk = 0; chunk < 4; ++chunk) {
        int cbase = blockStart + chunk * 64;

        // -------- phase A: MFMA tpw tile, wave handles cols [wave*128,+128) --
        uint4 B[4][2];
#pragma unroll
        for (int nt = 0; nt < 4; ++nt) {
            int esrc = elist[cbase + nt * 16 + lm];
            B[nt][0] = *(const uint4*)(h3w + (size_t)esrc * 64 + lq * 8);
            B[nt][1] = *(const uint4*)(h3w + (size_t)esrc * 64 + 32 + lq * 8);
        }
#pragma unroll
        for (int ml = 0; ml < 8; ++ml) {
            int m = wave * 8 + ml;
            f32x4 acc0 = {0.f, 0.f, 0.f, 0.f};
            f32x4 acc1 = {0.f, 0.f, 0.f, 0.f};
            f32x4 acc2 = {0.f, 0.f, 0.f, 0.f};
            f32x4 acc3 = {0.f, 0.f, 0.f, 0.f};
#pragma unroll
            for (int k = 0; k < 2; ++k) {
                short8 a = __builtin_bit_cast(short8, *(const uint4*)(aw + m * 1024 + k * 32));
                acc0 = __builtin_amdgcn_mfma_f32_16x16x32_bf16(a, __builtin_bit_cast(short8, B[0][k]), acc0, 0, 0, 0);
                acc1 = __builtin_amdgcn_mfma_f32_16x16x32_bf16(a, __builtin_bit_cast(short8, B[1][k]), acc1, 0, 0, 0);
                acc2 = __builtin_amdgcn_mfma_f32_16x16x32_bf16(a, __builtin_bit_cast(short8, B[2][k]), acc2, 0, 0, 0);
                acc3 = __builtin_amdgcn_mfma_f32_16x16x32_bf16(a, __builtin_bit_cast(short8, B[3][k]), acc3, 0, 0, 0);
            }
            int cb = m * 16 + lq * 4;
            uint2 v;
            v.x = pack2(acc0[0], acc0[1]); v.y = pack2(acc0[2], acc0[3]);
            *(uint2*)(tile + (0 * 16 + lm) * 520 + cb) = v;
            v.x = pack2(acc1[0], acc1[1]); v.y = pack2(acc1[2], acc1[3]);
            *(uint2*)(tile + (1 * 16 + lm) * 520 + cb) = v;
            v.x = pack2(acc2[0], acc2[1]); v.y = pack2(acc2[2], acc2[3]);
            *(uint2*)(tile + (2 * 16 + lm) * 520 + cb) = v;
            v.x = pack2(acc3[0], acc3[1]); v.y = pack2(acc3[2], acc3[3]);
            *(uint2*)(tile + (3 * 16 + lm) * 520 + cb) = v;
        }
        __syncthreads();

        // -------- phase B: tensor product + reduce from LDS --------
        for (int e = 0; e < 64; ++e) {
            int slot = cbase + e;                  // uniform
            int r = rix[slot];                     // uniform
            if (r != curR) { doFlush(curR); curR = r; }
            int snd = eis[slot];                   // uniform
            float4 eav = eap[slot];                // uniform
            float y0 = eav.x, y1x = eav.y, y1y = eav.z, y1z = eav.w;
            uint32_t wp = *(const uint32_t*)(tile + e * 520 + t * 2);
            float wa = bflo(wp), wb = bfhi(wp);
            const float* xr = xw + (size_t)snd * 512;
            if (j == 0) {
                a0 += wa * xr[c0] * y0;
                a1 += wb * xr[c0 + 1] * y0;
            } else if (j == 1) {
                float ta = wa * xr[c0], tb = wb * xr[c0 + 1];
                a0 += ta * y1x; a1 += ta * y1y; a2 += ta * y1z;
                a3 += tb * y1x; a4 += tb * y1y; a5 += tb * y1z;
            } else if (j == 2) {
                float f0 = wa * y0, f1 = wb * y0;
                a0 += f0 * xr[128 + c0]; a1 += f0 * xr[256 + c0]; a2 += f0 * xr[384 + c0];
                a3 += f1 * xr[128 + c0 + 1]; a4 += f1 * xr[256 + c0 + 1]; a5 += f1 * xr[384 + c0 + 1];
            } else {
                float dta = xr[128 + c0] * y1x + xr[256 + c0] * y1y + xr[384 + c0] * y1z;
                float dtb = xr[128 + c0 + 1] * y1x + xr[256 + c0 + 1] * y1y + xr[384 + c0 + 1] * y1z;
                a0 += wa * dta * 0.5773502691896258f;
                a1 += wb * dtb * 0.5773502691896258f;
            }
        }
        __syncthreads();
    }
    doFlush(curR);
}

// ---------------------------------------------------------------------------
// k_out0 (MFMA): o0 = msg0 @ Wo0 /16/10. msg now f32; pack A-frags on load.
// ---------------------------------------------------------------------------
__global__ __launch_bounds__(256) void k_out0(const float* __restrict__ msg,
                                              const unsigned short* __restrict__ woT,
                                              float* __restrict__ out) {
    int wave = threadIdx.x >> 6, lane = threadIdx.x & 63;
    int wid = blockIdx.x * 4 + wave;
    if (wid >= NN / 16) return;
    int n0 = wid * 16;
    int lm = lane & 15, lq = lane >> 4;
    uint4 A[8];
    const float* ar = msg + (size_t)(n0 + lm) * 1024 + lq * 8;
#pragma unroll
    for (int kf = 0; kf < 8; ++kf) {
        float4 f0 = *(const float4*)(ar + kf * 32);
        float4 f1 = *(const float4*)(ar + kf * 32 + 4);
        A[kf] = (uint4){pack2(f0.x, f0.y), pack2(f0.z, f0.w),
                        pack2(f1.x, f1.y), pack2(f1.z, f1.w)};
    }
    const unsigned short* br = woT + lm * 256 + lq * 8;
    float* ob = out + (size_t)n0 * 512;
    for (int vt = 0; vt < 8; ++vt) {
        f32x4 acc = {0.f, 0.f, 0.f, 0.f};
#pragma unroll
        for (int kf = 0; kf < 8; ++kf) {
            uint4 b = *(const uint4*)(br + vt * 16 * 256 + kf * 32);
            acc = __builtin_amdgcn_mfma_f32_16x16x32_bf16(
                __builtin_bit_cast(short8, A[kf]), __builtin_bit_cast(short8, b), acc, 0, 0, 0);
        }
#pragma unroll
        for (int r = 0; r < 4; ++r)
            ob[(size_t)(lq * 4 + r) * 512 + vt * 16 + lm] = acc[r] * 0.00625f;
    }
}

// ---------------------------------------------------------------------------
// k_out1 (MFMA): 3 GEMMs sharing B = woT1 -> out[n][128 + v*3 + m].
// ---------------------------------------------------------------------------
__global__ __launch_bounds__(256) void k_out1(const float* __restrict__ msg,
                                              const unsigned short* __restrict__ woT,
                                              float* __restrict__ out) {
    int wave = threadIdx.x >> 6, lane = threadIdx.x & 63;
    int wid = blockIdx.x * 4 + wave;
    if (wid >= NN / 16) return;
    int n0 = wid * 16;
    int lm = lane & 15, lq = lane >> 4;
    uint4 A[3][8];
    const float* ar = msg + (size_t)(n0 + lm) * 1024 + 256 + lq * 8;
#pragma unroll
    for (int m = 0; m < 3; ++m)
#pragma unroll
        for (int kf = 0; kf < 8; ++kf) {
            float4 f0 = *(const float4*)(ar + m * 256 + kf * 32);
            float4 f1 = *(const float4*)(ar + m * 256 + kf * 32 + 4);
            A[m][kf] = (uint4){pack2(f0.x, f0.y), pack2(f0.z, f0.w),
                               pack2(f1.x, f1.y), pack2(f1.z, f1.w)};
        }
    const unsigned short* br = woT + lm * 256 + lq * 8;
    float* ob = out + (size_t)n0 * 512 + 128;
    for (int vt = 0; vt < 8; ++vt) {
        f32x4 acc[3];
#pragma unroll
        for (int m = 0; m < 3; ++m) acc[m] = (f32x4){0.f, 0.f, 0.f, 0.f};
#pragma unroll
        for (int kf = 0; kf < 8; ++kf) {
            uint4 braw = *(const uint4*)(br + vt * 16 * 256 + kf * 32);
            short8 b = __builtin_bit_cast(short8, braw);
#pragma unroll
            for (int m = 0; m < 3; ++m)
                acc[m] = __builtin_amdgcn_mfma_f32_16x16x32_bf16(
                    __builtin_bit_cast(short8, A[m][kf]), b, acc[m], 0, 0, 0);
        }
        int vb = (vt * 16 + lm) * 3;
#pragma unroll
        for (int r = 0; r < 4; ++r) {
            float* o = ob + (size_t)(lq * 4 + r) * 512 + vb;
            o[0] = acc[0][r] * 0.00625f;
            o[1] = acc[1][r] * 0.00625f;
            o[2] = acc[2][r] * 0.00625f;
        }
    }
}

// ---------------------------------------------------------------------------
extern "C" void kernel_launch(void* const* d_in, const int* in_sizes, int n_in,
                              void* d_out, int out_size, void* d_ws, size_t ws_size,
                              hipStream_t stream) {
    const float* nf  = (const float*)d_in[0];
    const float* ea  = (const float*)d_in[1];
    const float* ef  = (const float*)d_in[2];
    const int*   ei  = (const int*)d_in[3];
    const float* Wu0 = (const float*)d_in[4];
    const float* Wu1 = (const float*)d_in[5];
    const float* W1  = (const float*)d_in[6];
    const float* W2  = (const float*)d_in[7];
    const float* W3  = (const float*)d_in[8];
    const float* W4  = (const float*)d_in[9];
    const float* Wo0 = (const float*)d_in[10];
    const float* Wo1 = (const float*)d_in[11];
    float* out = (float*)d_out;
    char* ws = (char*)d_ws;

    // Layout (~97 MB, no tpw):
    float*          xw   = (float*)ws;                              // 20.48 MB
    unsigned short* h3w  = (unsigned short*)(ws + 20480000);        // 20.48 MB
    float*          msg  = (float*)(ws + 40960000);                 // 40.96 MB
    unsigned short* x0b  = (unsigned short*)(ws + 81920000);        // 2.56 MB
    unsigned short* x1b  = (unsigned short*)(ws + 84480000);        // 7.68 MB
    unsigned short* w4T  = (unsigned short*)(ws + 92160000);        // 64 KB
    unsigned short* woT0 = (unsigned short*)(ws + 92225536);        // 64 KB
    unsigned short* woT1 = (unsigned short*)(ws + 92291072);        // 64 KB
    float4*         eap  = (float4*)(ws + 92356608);                // 2.56 MB
    int* ib     = (int*)(ws + 94916608);
    int* counts = ib;                 // NN
    int* offs   = ib + 10240;         // NN+1
    int* cursor = ib + 20480;         // NN
    int* elist  = ib + 30720;         // NE
    int* rix    = ib + 190720;        // NE
    int* eis    = ib + 350720;        // NE -> ends at byte 94916608+2042880
    unsigned short* w1Tp = (unsigned short*)(ws + 96959488);        // 4 KB
    unsigned short* w2T  = (unsigned short*)(ws + 96963584);        // 8 KB
    unsigned short* w3T  = (unsigned short*)(ws + 96971776);        // 8 KB
    unsigned short* w0T  = (unsigned short*)(ws + 96979968);        // 32 KB
    unsigned short* w1T  = (unsigned short*)(ws + 97012736);        // 32 KB

    k_wmlp <<<1, 256, 0, stream>>>(W1, W2, W3, w1Tp, w2T, w3T);
    k_wup  <<<64, 256, 0, stream>>>(Wu0, Wu1, w0T, w1T);
    k_prep <<<5000, 256, 0, stream>>>(nf, x0b, x1b);
    k_upg  <<<313, 256, 0, stream>>>(x0b, x1b, w0T, w1T, xw);
    k_mlp  <<<625, 256, 0, stream>>>(ef, w1Tp, w2T, w3T, h3w);
    k_w4t  <<<128, 256, 0, stream>>>(W4, w4T);
    k_wt2  <<<128, 256, 0, stream>>>(Wo0, Wo1, woT0, woT1);
    k_zero <<<40, 256, 0, stream>>>(counts, NN);
    k_hist <<<625, 256, 0, stream>>>(ei, counts);
    k_scan <<<1, 1024, 0, stream>>>(counts, offs, cursor);
    k_fill <<<625, 256, 0, stream>>>(ei, cursor, elist, rix);
    k_gather<<<625, 256, 0, stream>>>(ei, ea, elist, eis, eap);
    hipMemsetAsync(msg, 0, 40960000, stream);
    k_tpmsg<<<625, 256, 0, stream>>>(h3w, w4T, elist, eis, rix, eap, offs, xw, msg);
    k_out0 <<<157, 256, 0, stream>>>(msg, woT0, out);
    k_out1 <<<157, 256, 0, stream>>>(msg, woT1, out);
}

// Round 11
// 384.139 us; speedup vs baseline: 1.3370x; 1.3370x over previous
//
#include <hip/hip_runtime.h>
#include <stdint.h>

#define NN 10000
#define NE 160000

typedef short short8 __attribute__((ext_vector_type(8)));
typedef float f32x4 __attribute__((ext_vector_type(4)));

// ---------- bf16 helpers (internal staging format; I/O is f32) ----------
__device__ __forceinline__ float bf2f(unsigned short u) {
    return __uint_as_float(((uint32_t)u) << 16);
}
__device__ __forceinline__ float bflo(uint32_t u) { return __uint_as_float(u << 16); }
__device__ __forceinline__ float bfhi(uint32_t u) { return __uint_as_float(u & 0xffff0000u); }
__device__ __forceinline__ unsigned short f2bf(float f) {
    uint32_t u = __float_as_uint(f);
    u += 0x7fffu + ((u >> 16) & 1u);   // RNE
    return (unsigned short)(u >> 16);
}
__device__ __forceinline__ uint32_t pack2(float lo, float hi) {
    return (uint32_t)f2bf(lo) | ((uint32_t)f2bf(hi) << 16);
}
__device__ __forceinline__ float silu2(float x) {
    return 1.679177f * x / (1.f + __expf(-x));
}

// ---------------------------------------------------------------------------
// k_wup: transpose up-weights -> [v][u] bf16 with 1/sqrt(128) folded in.
// ---------------------------------------------------------------------------
__global__ __launch_bounds__(256) void k_wup(const float* __restrict__ Wu0,
                                             const float* __restrict__ Wu1,
                                             unsigned short* __restrict__ w0T,
                                             unsigned short* __restrict__ w1T) {
    const float s = 0.08838834764831845f;
    for (int i = threadIdx.x + blockIdx.x * 256; i < 16384; i += 256 * 64) {
        int u = i >> 7, v = i & 127;
        w0T[v * 128 + u] = f2bf(Wu0[i] * s);
        w1T[v * 128 + u] = f2bf(Wu1[i] * s);
    }
}

// ---------------------------------------------------------------------------
// k_prep: nf (f32, [n][512]) -> bf16 MFMA A-planes.
// ---------------------------------------------------------------------------
__global__ __launch_bounds__(256) void k_prep(const float* __restrict__ nf,
                                              unsigned short* __restrict__ x0b,
                                              unsigned short* __restrict__ x1b) {
    int idx = blockIdx.x * 256 + threadIdx.x;     // 1,280,000
    int n = idx >> 7, u = idx & 127;
    const float* row = nf + (size_t)n * 512;
    x0b[(size_t)n * 128 + u] = f2bf(row[u]);
    const float* p = row + 128 + u * 3;
    x1b[(size_t)n * 128 + u]                = f2bf(p[0]);
    x1b[1280000 + (size_t)n * 128 + u]      = f2bf(p[1]);
    x1b[2560000 + (size_t)n * 128 + u]      = f2bf(p[2]);
}

// ---------------------------------------------------------------------------
// k_upg (MFMA): y0 = x0 @ W0, y1[m] = x1[m] @ W1. (R9 proven)
// xw[n]: [y0 (128) | y1 m-major: 128 + m*128 + v]
// ---------------------------------------------------------------------------
__global__ __launch_bounds__(256) void k_upg(const unsigned short* __restrict__ x0b,
                                             const unsigned short* __restrict__ x1b,
                                             const unsigned short* __restrict__ w0T,
                                             const unsigned short* __restrict__ w1T,
                                             float* __restrict__ xw) {
    int wave = threadIdx.x >> 6, lane = threadIdx.x & 63;
    int wid = blockIdx.x * 4 + wave;              // 1250
    if (wid >= 1250) return;
    int tile = wid >> 1, half = wid & 1;
    int n0 = tile * 16;
    int lm = lane & 15, lq = lane >> 4;

    uint4 A0[4], A1[3][4];
    const unsigned short* a0r = x0b + (size_t)(n0 + lm) * 128 + lq * 8;
#pragma unroll
    for (int kf = 0; kf < 4; ++kf) A0[kf] = *(const uint4*)(a0r + kf * 32);
#pragma unroll
    for (int m = 0; m < 3; ++m) {
        const unsigned short* a1r = x1b + 1280000 * (size_t)m + (size_t)(n0 + lm) * 128 + lq * 8;
#pragma unroll
        for (int kf = 0; kf < 4; ++kf) A1[m][kf] = *(const uint4*)(a1r + kf * 32);
    }

    for (int vq = 0; vq < 4; ++vq) {
        int vt = half * 4 + vq;
        const unsigned short* b0r = w0T + (vt * 16 + lm) * 128 + lq * 8;
        const unsigned short* b1r = w1T + (vt * 16 + lm) * 128 + lq * 8;
        f32x4 acc0 = {0.f, 0.f, 0.f, 0.f};
#pragma unroll
        for (int kf = 0; kf < 4; ++kf) {
            short8 b = __builtin_bit_cast(short8, *(const uint4*)(b0r + kf * 32));
            acc0 = __builtin_amdgcn_mfma_f32_16x16x32_bf16(
                __builtin_bit_cast(short8, A0[kf]), b, acc0, 0, 0, 0);
        }
        f32x4 acc1[3];
#pragma unroll
        for (int m = 0; m < 3; ++m) acc1[m] = (f32x4){0.f, 0.f, 0.f, 0.f};
#pragma unroll
        for (int kf = 0; kf < 4; ++kf) {
            short8 b = __builtin_bit_cast(short8, *(const uint4*)(b1r + kf * 32));
#pragma unroll
            for (int m = 0; m < 3; ++m)
                acc1[m] = __builtin_amdgcn_mfma_f32_16x16x32_bf16(
                    __builtin_bit_cast(short8, A1[m][kf]), b, acc1[m], 0, 0, 0);
        }
        int col = vt * 16 + lm;
#pragma unroll
        for (int r = 0; r < 4; ++r) {
            float* o = xw + (size_t)(n0 + lq * 4 + r) * 512;
            o[col] = acc0[r];
            o[128 + col] = acc1[0][r];
            o[256 + col] = acc1[1][r];
            o[384 + col] = acc1[2][r];
        }
    }
}

// ---------------------------------------------------------------------------
// k_wmlp: pre-transpose+scale MLP weights to bf16.
// ---------------------------------------------------------------------------
__global__ __launch_bounds__(256) void k_wmlp(const float* __restrict__ W1,
                                              const float* __restrict__ W2,
                                              const float* __restrict__ W3,
                                              unsigned short* __restrict__ w1Tp,
                                              unsigned short* __restrict__ w2T,
                                              unsigned short* __restrict__ w3T) {
    int t = threadIdx.x;
    for (int i = t; i < 2048; i += 256) {
        int jj = i >> 5, k = i & 31;
        w1Tp[i] = (k < 8) ? f2bf(W1[k * 64 + jj] * 0.3535533905932738f) : 0;
    }
    for (int i = t; i < 4096; i += 256) {
        int jj = i >> 6, k = i & 63;
        w2T[i] = f2bf(W2[k * 64 + jj] * 0.125f);
        w3T[i] = f2bf(W3[k * 64 + jj] * 0.125f);
    }
}

// ---------------------------------------------------------------------------
// K2 (MFMA): edge MLP stages 1-3 -> h3 (NE x 64 bf16). (R7 proven)
// ---------------------------------------------------------------------------
__global__ __launch_bounds__(256) void k_mlp(const float* __restrict__ ef,
                                             const unsigned short* __restrict__ w1Tp,
                                             const unsigned short* __restrict__ w2T,
                                             const unsigned short* __restrict__ w3T,
                                             unsigned short* __restrict__ h3w) {
    __shared__ __align__(16) unsigned short hs_all[4][64 * 72];
    int wave = threadIdx.x >> 6, lane = threadIdx.x & 63;
    int lm = lane & 15, lq = lane >> 4;
    int e0 = blockIdx.x * 256 + wave * 64;
    unsigned short* h = hs_all[wave];

    // stage 1: K=32 (8 real, zero-padded)
    uint4 A1[4];
#pragma unroll
    for (int mt = 0; mt < 4; ++mt)
        A1[mt] = *(const uint4*)(w1Tp + (mt * 16 + lm) * 32 + lq * 8);
#pragma unroll
    for (int nt = 0; nt < 4; ++nt) {
        uint4 b = {0, 0, 0, 0};
        if (lq == 0) {
            const float4* p = (const float4*)(ef + (size_t)(e0 + nt * 16 + lm) * 8);
            float4 x = p[0], y = p[1];
            b.x = pack2(x.x, x.y); b.y = pack2(x.z, x.w);
            b.z = pack2(y.x, y.y); b.w = pack2(y.z, y.w);
        }
        short8 bb = __builtin_bit_cast(short8, b);
        unsigned short* hrow = h + (nt * 16 + lm) * 72;
#pragma unroll
        for (int mt = 0; mt < 4; ++mt) {
            f32x4 acc = {0.f, 0.f, 0.f, 0.f};
            acc = __builtin_amdgcn_mfma_f32_16x16x32_bf16(
                __builtin_bit_cast(short8, A1[mt]), bb, acc, 0, 0, 0);
            uint2 v;
            v.x = pack2(silu2(acc[0]), silu2(acc[1]));
            v.y = pack2(silu2(acc[2]), silu2(acc[3]));
            *(uint2*)(hrow + mt * 16 + lq * 4) = v;
        }
    }

    // stage 2: K=64
    uint4 A2[4][2];
#pragma unroll
    for (int mt = 0; mt < 4; ++mt)
#pragma unroll
        for (int kf = 0; kf < 2; ++kf)
            A2[mt][kf] = *(const uint4*)(w2T + (mt * 16 + lm) * 64 + kf * 32 + lq * 8);
#pragma unroll
    for (int nt = 0; nt < 4; ++nt) {
        unsigned short* hrow = h + (nt * 16 + lm) * 72;
        short8 B0 = __builtin_bit_cast(short8, *(const uint4*)(hrow + lq * 8));
        short8 B1 = __builtin_bit_cast(short8, *(const uint4*)(hrow + 32 + lq * 8));
#pragma unroll
        for (int mt = 0; mt < 4; ++mt) {
            f32x4 acc = {0.f, 0.f, 0.f, 0.f};
            acc = __builtin_amdgcn_mfma_f32_16x16x32_bf16(
                __builtin_bit_cast(short8, A2[mt][0]), B0, acc, 0, 0, 0);
            acc = __builtin_amdgcn_mfma_f32_16x16x32_bf16(
                __builtin_bit_cast(short8, A2[mt][1]), B1, acc, 0, 0, 0);
            uint2 v;
            v.x = pack2(silu2(acc[0]), silu2(acc[1]));
            v.y = pack2(silu2(acc[2]), silu2(acc[3]));
            *(uint2*)(hrow + mt * 16 + lq * 4) = v;
        }
    }

    // stage 3: K=64
    uint4 A3[4][2];
#pragma unroll
    for (int mt = 0; mt < 4; ++mt)
#pragma unroll
        for (int kf = 0; kf < 2; ++kf)
            A3[mt][kf] = *(const uint4*)(w3T + (mt * 16 + lm) * 64 + kf * 32 + lq * 8);
#pragma unroll
    for (int nt = 0; nt < 4; ++nt) {
        unsigned short* hrow = h + (nt * 16 + lm) * 72;
        short8 B0 = __builtin_bit_cast(short8, *(const uint4*)(hrow + lq * 8));
        short8 B1 = __builtin_bit_cast(short8, *(const uint4*)(hrow + 32 + lq * 8));
#pragma unroll
        for (int mt = 0; mt < 4; ++mt) {
            f32x4 acc = {0.f, 0.f, 0.f, 0.f};
            acc = __builtin_amdgcn_mfma_f32_16x16x32_bf16(
                __builtin_bit_cast(short8, A3[mt][0]), B0, acc, 0, 0, 0);
            acc = __builtin_amdgcn_mfma_f32_16x16x32_bf16(
                __builtin_bit_cast(short8, A3[mt][1]), B1, acc, 0, 0, 0);
            uint2 v;
            v.x = pack2(silu2(acc[0]), silu2(acc[1]));
            v.y = pack2(silu2(acc[2]), silu2(acc[3]));
            *(uint2*)(hrow + mt * 16 + lq * 4) = v;
        }
    }

    // flush: coalesced 16B/lane stores
    const unsigned short* hr = h + lane * 72;
    uint4* og = (uint4*)(h3w + (size_t)(e0 + lane) * 64);
#pragma unroll
    for (int q = 0; q < 8; ++q) og[q] = *(const uint4*)(hr + q * 8);
}

// ---------------------------------------------------------------------------
// K3: CSR build by receiver (zero -> histogram -> scan -> fill)
// ---------------------------------------------------------------------------
__global__ void k_zero(int* __restrict__ p, int n) {
    int i = blockIdx.x * 256 + threadIdx.x;
    if (i < n) p[i] = 0;
}
__global__ void k_hist(const int* __restrict__ ei, int* __restrict__ counts) {
    int e = blockIdx.x * 256 + threadIdx.x;
    if (e < NE) atomicAdd(&counts[ei[NE + e]], 1);
}
__global__ __launch_bounds__(1024) void k_scan(const int* __restrict__ counts,
                                               int* __restrict__ offs,
                                               int* __restrict__ cursor) {
    __shared__ int sums[1024];
    int t = threadIdx.x;
    int base = t * 10;
    int s = 0;
    for (int i = 0; i < 10; ++i) {
        int idx = base + i;
        if (idx < NN) s += counts[idx];
    }
    sums[t] = s;
    __syncthreads();
    for (int d = 1; d < 1024; d <<= 1) {
        int v = (t >= d) ? sums[t - d] : 0;
        __syncthreads();
        if (t >= d) sums[t] += v;
        __syncthreads();
    }
    int run = (t == 0) ? 0 : sums[t - 1];
    for (int i = 0; i < 10; ++i) {
        int idx = base + i;
        if (idx < NN) {
            offs[idx] = run;
            cursor[idx] = run;
            run += counts[idx];
        }
    }
    if (t == 0) offs[NN] = NE;
}
__global__ void k_fill(const int* __restrict__ ei, int* __restrict__ cursor,
                       int* __restrict__ elist) {
    int e = blockIdx.x * 256 + threadIdx.x;
    if (e < NE) {
        int slot = atomicAdd(&cursor[ei[NE + e]], 1);
        elist[slot] = e;
    }
}
// k_gather: resolve per-slot sender + edge_attrs
__global__ void k_gather(const int* __restrict__ ei, const float* __restrict__ ea,
                         const int* __restrict__ elist,
                         int* __restrict__ eis, float4* __restrict__ eap) {
    int i = blockIdx.x * 256 + threadIdx.x;
    if (i < NE) {
        int e = elist[i];
        eis[i] = ei[e];
        eap[i] = *(const float4*)(ea + (size_t)e * 4);
    }
}

// ---------------------------------------------------------------------------
// Weight transposes (bf16).
// ---------------------------------------------------------------------------
__global__ void k_w4t(const float* __restrict__ W4, unsigned short* __restrict__ w4T) {
    int idx = blockIdx.x * 256 + threadIdx.x;   // 32768
    int k = idx >> 9, c = idx & 511;
    w4T[c * 64 + k] = f2bf(W4[idx]);
}
__global__ void k_wt2(const float* __restrict__ Wo0, const float* __restrict__ Wo1,
                      unsigned short* __restrict__ woT0, unsigned short* __restrict__ woT1) {
    int idx = blockIdx.x * 256 + threadIdx.x;   // 32768
    int u = idx >> 7, v = idx & 127;
    woT0[v * 256 + u] = f2bf(Wo0[idx]);
    woT1[v * 256 + u] = f2bf(Wo1[idx]);
}

// ---------------------------------------------------------------------------
// k_tpw (PERMUTED + PLANE LAYOUT): tpw is stored as 4 column-planes
//   tpwp[j][slot][128]  (j = c>>7, local col = c&127)
// so that k_msg2's wave j streams slot-consecutive 256B lines.
// tpw_perm[slot] = (h3[elist[slot]] . W4[:,c]) / 8 via MFMA (R5-verified).
// ---------------------------------------------------------------------------
__global__ __launch_bounds__(256) void k_tpw(const unsigned short* __restrict__ h3w,
                                             const unsigned short* __restrict__ w4T,
                                             const int* __restrict__ elist,
                                             unsigned short* __restrict__ tpw) {
    int wave = threadIdx.x >> 6, lane = threadIdx.x & 63;
    int e0 = blockIdx.x * 256 + wave * 64;
    int lm = lane & 15, lq = lane >> 4;
    uint4 B[4][2];
#pragma unroll
    for (int n = 0; n < 4; ++n) {
        int esrc = elist[e0 + n * 16 + lm];
#pragma unroll
        for (int k = 0; k < 2; ++k)
            B[n][k] = *(const uint4*)(h3w + (size_t)esrc * 64 + k * 32 + lq * 8);
    }
    const unsigned short* aw = w4T + lm * 64 + lq * 8;
#pragma unroll 2
    for (int m = 0; m < 32; ++m) {
        f32x4 acc0 = {0.f, 0.f, 0.f, 0.f};
        f32x4 acc1 = {0.f, 0.f, 0.f, 0.f};
        f32x4 acc2 = {0.f, 0.f, 0.f, 0.f};
        f32x4 acc3 = {0.f, 0.f, 0.f, 0.f};
#pragma unroll
        for (int k = 0; k < 2; ++k) {
            uint4 a_raw = *(const uint4*)(aw + m * 1024 + k * 32);
            short8 a = __builtin_bit_cast(short8, a_raw);
            acc0 = __builtin_amdgcn_mfma_f32_16x16x32_bf16(a, __builtin_bit_cast(short8, B[0][k]), acc0, 0, 0, 0);
            acc1 = __builtin_amdgcn_mfma_f32_16x16x32_bf16(a, __builtin_bit_cast(short8, B[1][k]), acc1, 0, 0, 0);
            acc2 = __builtin_amdgcn_mfma_f32_16x16x32_bf16(a, __builtin_bit_cast(short8, B[2][k]), acc2, 0, 0, 0);
            acc3 = __builtin_amdgcn_mfma_f32_16x16x32_bf16(a, __builtin_bit_cast(short8, B[3][k]), acc3, 0, 0, 0);
        }
        int cb = m * 16 + lq * 4;                 // global col 0..511
        int plane = cb >> 7, cl = cb & 127;
        unsigned short* pb = tpw + (size_t)plane * NE * 128 + cl;
        uint2 v;
        v.x = pack2(acc0[0] * 0.125f, acc0[1] * 0.125f);
        v.y = pack2(acc0[2] * 0.125f, acc0[3] * 0.125f);
        *(uint2*)(pb + (size_t)(e0 + 0 * 16 + lm) * 128) = v;
        v.x = pack2(acc1[0] * 0.125f, acc1[1] * 0.125f);
        v.y = pack2(acc1[2] * 0.125f, acc1[3] * 0.125f);
        *(uint2*)(pb + (size_t)(e0 + 1 * 16 + lm) * 128) = v;
        v.x = pack2(acc2[0] * 0.125f, acc2[1] * 0.125f);
        v.y = pack2(acc2[2] * 0.125f, acc2[3] * 0.125f);
        *(uint2*)(pb + (size_t)(e0 + 2 * 16 + lm) * 128) = v;
        v.x = pack2(acc3[0] * 0.125f, acc3[1] * 0.125f);
        v.y = pack2(acc3[2] * 0.125f, acc3[3] * 0.125f);
        *(uint2*)(pb + (size_t)(e0 + 3 * 16 + lm) * 128) = v;
    }
}

// ---------------------------------------------------------------------------
// k_msg2: tensor product + reduce. Wave j streams its 256B/slot plane
// contiguously; eis/eap sequential; xw gather L2/L3-resident.
// ---------------------------------------------------------------------------
__global__ __launch_bounds__(256) void k_msg2(const float* __restrict__ xw,
                                              const unsigned short* __restrict__ tpw,
                                              const int* __restrict__ eis,
                                              const float4* __restrict__ eap,
                                              const int* __restrict__ offs,
                                              unsigned short* __restrict__ msgb) {
    int n = blockIdx.x, t = threadIdx.x;
    int j = t >> 6, c0 = (t & 63) * 2;
    int beg = offs[n], end = offs[n + 1];
    const unsigned short* plane = tpw + (size_t)j * NE * 128;
    float a0 = 0.f, a1 = 0.f, a2 = 0.f, a3 = 0.f, a4 = 0.f, a5 = 0.f;
    for (int i = beg; i < end; ++i) {
        int snd = eis[i];
        float4 eav = eap[i];
        float y0 = eav.x, y1x = eav.y, y1y = eav.z, y1z = eav.w;
        uint32_t wp = *(const uint32_t*)(plane + (size_t)i * 128 + c0);
        float wa = bflo(wp), wb = bfhi(wp);
        const float* xr = xw + (size_t)snd * 512;
        if (j == 0) {
            a0 += wa * xr[c0] * y0;
            a1 += wb * xr[c0 + 1] * y0;
        } else if (j == 1) {
            float ta = wa * xr[c0], tb = wb * xr[c0 + 1];
            a0 += ta * y1x; a1 += ta * y1y; a2 += ta * y1z;
            a3 += tb * y1x; a4 += tb * y1y; a5 += tb * y1z;
        } else if (j == 2) {
            float f0 = wa * y0, f1 = wb * y0;
            a0 += f0 * xr[128 + c0]; a1 += f0 * xr[256 + c0]; a2 += f0 * xr[384 + c0];
            a3 += f1 * xr[128 + c0 + 1]; a4 += f1 * xr[256 + c0 + 1]; a5 += f1 * xr[384 + c0 + 1];
        } else {
            float dta = xr[128 + c0] * y1x + xr[256 + c0] * y1y + xr[384 + c0] * y1z;
            float dtb = xr[128 + c0 + 1] * y1x + xr[256 + c0 + 1] * y1y + xr[384 + c0 + 1] * y1z;
            a0 += wa * dta * 0.5773502691896258f;
            a1 += wb * dtb * 0.5773502691896258f;
        }
    }
    unsigned short* mr = msgb + (size_t)n * 1024;
    if (j == 0) {
        *(uint32_t*)(mr + c0) = pack2(a0, a1);
    } else if (j == 1) {
        *(uint32_t*)(mr + 256 + c0)       = pack2(a0, a3);
        *(uint32_t*)(mr + 256 + 256 + c0) = pack2(a1, a4);
        *(uint32_t*)(mr + 256 + 512 + c0) = pack2(a2, a5);
    } else if (j == 2) {
        *(uint32_t*)(mr + 256 + 128 + c0)       = pack2(a0, a3);
        *(uint32_t*)(mr + 256 + 256 + 128 + c0) = pack2(a1, a4);
        *(uint32_t*)(mr + 256 + 512 + 128 + c0) = pack2(a2, a5);
    } else {
        *(uint32_t*)(mr + 128 + c0) = pack2(a0, a1);
    }
}

// ---------------------------------------------------------------------------
// k_out0 (MFMA): o0 = msg0 @ Wo0 /16/10.  M=10000 nodes, N=128, K=256.
// ---------------------------------------------------------------------------
__global__ __launch_bounds__(256) void k_out0(const unsigned short* __restrict__ msgb,
                                              const unsigned short* __restrict__ woT,
                                              float* __restrict__ out) {
    int wave = threadIdx.x >> 6, lane = threadIdx.x & 63;
    int wid = blockIdx.x * 4 + wave;
    if (wid >= NN / 16) return;
    int n0 = wid * 16;
    int lm = lane & 15, lq = lane >> 4;
    uint4 A[8];
    const unsigned short* ar = msgb + (size_t)(n0 + lm) * 1024 + lq * 8;
#pragma unroll
    for (int kf = 0; kf < 8; ++kf) A[kf] = *(const uint4*)(ar + kf * 32);
    const unsigned short* br = woT + lm * 256 + lq * 8;
    float* ob = out + (size_t)n0 * 512;
    for (int vt = 0; vt < 8; ++vt) {
        f32x4 acc = {0.f, 0.f, 0.f, 0.f};
#pragma unroll
        for (int kf = 0; kf < 8; ++kf) {
            uint4 b = *(const uint4*)(br + vt * 16 * 256 + kf * 32);
            acc = __builtin_amdgcn_mfma_f32_16x16x32_bf16(
                __builtin_bit_cast(short8, A[kf]), __builtin_bit_cast(short8, b), acc, 0, 0, 0);
        }
#pragma unroll
        for (int r = 0; r < 4; ++r)
            ob[(size_t)(lq * 4 + r) * 512 + vt * 16 + lm] = acc[r] * 0.00625f;
    }
}

// ---------------------------------------------------------------------------
// k_out1 (MFMA): 3 GEMMs sharing B = woT1 -> out[n][128 + v*3 + m].
// ---------------------------------------------------------------------------
__global__ __launch_bounds__(256) void k_out1(const unsigned short* __restrict__ msgb,
                                              const unsigned short* __restrict__ woT,
                                              float* __restrict__ out) {
    int wave = threadIdx.x >> 6, lane = threadIdx.x & 63;
    int wid = blockIdx.x * 4 + wave;
    if (wid >= NN / 16) return;
    int n0 = wid * 16;
    int lm = lane & 15, lq = lane >> 4;
    uint4 A[3][8];
    const unsigned short* ar = msgb + (size_t)(n0 + lm) * 1024 + 256 + lq * 8;
#pragma unroll
    for (int m = 0; m < 3; ++m)
#pragma unroll
        for (int kf = 0; kf < 8; ++kf)
            A[m][kf] = *(const uint4*)(ar + m * 256 + kf * 32);
    const unsigned short* br = woT + lm * 256 + lq * 8;
    float* ob = out + (size_t)n0 * 512 + 128;
    for (int vt = 0; vt < 8; ++vt) {
        f32x4 acc[3];
#pragma unroll
        for (int m = 0; m < 3; ++m) acc[m] = (f32x4){0.f, 0.f, 0.f, 0.f};
#pragma unroll
        for (int kf = 0; kf < 8; ++kf) {
            uint4 braw = *(const uint4*)(br + vt * 16 * 256 + kf * 32);
            short8 b = __builtin_bit_cast(short8, braw);
#pragma unroll
            for (int m = 0; m < 3; ++m)
                acc[m] = __builtin_amdgcn_mfma_f32_16x16x32_bf16(
                    __builtin_bit_cast(short8, A[m][kf]), b, acc[m], 0, 0, 0);
        }
        int vb = (vt * 16 + lm) * 3;
#pragma unroll
        for (int r = 0; r < 4; ++r) {
            float* o = ob + (size_t)(lq * 4 + r) * 512 + vb;
            o[0] = acc[0][r] * 0.00625f;
            o[1] = acc[1][r] * 0.00625f;
            o[2] = acc[2][r] * 0.00625f;
        }
    }
}

// ---------------------------------------------------------------------------
extern "C" void kernel_launch(void* const* d_in, const int* in_sizes, int n_in,
                              void* d_out, int out_size, void* d_ws, size_t ws_size,
                              hipStream_t stream) {
    const float* nf  = (const float*)d_in[0];
    const float* ea  = (const float*)d_in[1];
    const float* ef  = (const float*)d_in[2];
    const int*   ei  = (const int*)d_in[3];
    const float* Wu0 = (const float*)d_in[4];
    const float* Wu1 = (const float*)d_in[5];
    const float* W1  = (const float*)d_in[6];
    const float* W2  = (const float*)d_in[7];
    const float* W3  = (const float*)d_in[8];
    const float* W4  = (const float*)d_in[9];
    const float* Wo0 = (const float*)d_in[10];
    const float* Wo1 = (const float*)d_in[11];
    float* out = (float*)d_out;
    char* ws = (char*)d_ws;

    // Layout (R9-proven, ws >= 226.2 MB):
    //   tpw planes [0, 163.84M)  xw [163.84M, 184.32M)  h3 [184.32M, 204.8M)
    //   msg [204.8M, 225.28M)  w4T [225.28M, +64K)  CSR ints  small weights.
    //   x0b/x1b alias tpw head (dead before k_tpw);
    //   woT0/woT1 + eis/eap alias h3 (dead after k_tpw).
    unsigned short* tpw  = (unsigned short*)ws;
    unsigned short* x0b  = (unsigned short*)ws;                 // 2.56 MB
    unsigned short* x1b  = (unsigned short*)(ws + 2560000);     // 7.68 MB
    float*          xw   = (float*)(ws + 163840000);
    unsigned short* h3w  = (unsigned short*)(ws + 184320000);
    unsigned short* woT0 = (unsigned short*)(ws + 184320000);
    unsigned short* woT1 = (unsigned short*)(ws + 184320000 + 65536);
    float4*         eap  = (float4*)(ws + 184320000 + 131072);            // NE*16B
    int*            eis  = (int*)(ws + 184320000 + 131072 + 2560000);     // NE*4B
    unsigned short* msgb = (unsigned short*)(ws + 204800000);
    unsigned short* w4T  = (unsigned short*)(ws + 225280000);
    int* ib     = (int*)(ws + 225280000 + 65536);
    int* counts = ib;                        // NN
    int* offs   = ib + 10240;                // NN+1
    int* cursor = ib + 20480;                // NN
    int* elist  = ib + 30720;                // NE
    unsigned short* w1Tp = (unsigned short*)(ws + 226108416);          // 64x32
    unsigned short* w2T  = (unsigned short*)(ws + 226108416 + 4096);   // 64x64
    unsigned short* w3T  = (unsigned short*)(ws + 226108416 + 12288);  // 64x64
    unsigned short* w0T  = (unsigned short*)(ws + 226128896);          // 128x128 (32KB)
    unsigned short* w1T  = (unsigned short*)(ws + 226161664);          // 128x128 (32KB)

    k_wmlp <<<1, 256, 0, stream>>>(W1, W2, W3, w1Tp, w2T, w3T);
    k_wup  <<<64, 256, 0, stream>>>(Wu0, Wu1, w0T, w1T);
    k_prep <<<5000, 256, 0, stream>>>(nf, x0b, x1b);
    k_upg  <<<313, 256, 0, stream>>>(x0b, x1b, w0T, w1T, xw);
    k_mlp  <<<625, 256, 0, stream>>>(ef, w1Tp, w2T, w3T, h3w);
    k_w4t  <<<128, 256, 0, stream>>>(W4, w4T);
    k_zero <<<40, 256, 0, stream>>>(counts, NN);
    k_hist <<<625, 256, 0, stream>>>(ei, counts);
    k_scan <<<1, 1024, 0, stream>>>(counts, offs, cursor);
    k_fill <<<625, 256, 0, stream>>>(ei, cursor, elist);
    k_tpw  <<<625, 256, 0, stream>>>(h3w, w4T, elist, tpw);
    k_wt2  <<<128, 256, 0, stream>>>(Wo0, Wo1, woT0, woT1);   // h3 dead now
    k_gather<<<625, 256, 0, stream>>>(ei, ea, elist, eis, eap);
    k_msg2 <<<NN, 256, 0, stream>>>(xw, tpw, eis, eap, offs, msgb);
    k_out0 <<<157, 256, 0, stream>>>(msgb, woT0, out);
    k_out1 <<<157, 256, 0, stream>>>(msgb, woT1, out);
}